// Round 14
// baseline (167.981 us; speedup 1.0000x reference)
//
#include <hip/hip_runtime.h>
#include <hip/hip_bf16.h>

#define NUM_CLASS 21
#define EPSF 1e-6f
// Problem dims (fixed by setup_inputs): B=8, D=512, H=W=128 -> HW=16384
#define BATCH 8
#define DCH 512
#define HW 16384
#define NDG 32                          // d-groups of 16
#define BNCD (BATCH * NUM_CLASS * DCH)  // 86016

typedef __attribute__((ext_vector_type(8))) short bf16x8;   // 8 bf16 = 4 VGPR
typedef __attribute__((ext_vector_type(4))) float f32x4;

__device__ __forceinline__ float waveReduce(float v) {
    #pragma unroll
    for (int m = 1; m < 64; m <<= 1) v += __shfl_xor(v, m, 64);
    return v;
}

// ---------------------------------------------------------------------------
// One K-tile (32 p, 8 per lane): bf16 feature fragment (single precision —
// error budget: sigma(S)~0.06, out[0] err ~1e-5 vs 10.24 threshold) + two
// onehot A fragments (classes ln, ln+16), 2 MFMAs. k-mapping inside the
// fragment cancels (A and B use identical (lane,reg) positions); C/D layout
// is the m89-verified one — this exact path produced absmax 0.0 in round 8.
// ---------------------------------------------------------------------------
__device__ __forceinline__ void procTile(
    float4 f0, float4 f1, int4 la, int4 lb, int ln,
    f32x4& acc0, f32x4& acc1, float& ss)
{
    bf16x8 fb, a0, a1;
    const float fv[8] = {f0.x, f0.y, f0.z, f0.w, f1.x, f1.y, f1.z, f1.w};
    const int   lv[8] = {la.x, la.y, la.z, la.w, lb.x, lb.y, lb.z, lb.w};
    #pragma unroll
    for (int j = 0; j < 8; ++j) {
        fb[j] = (short)(__float_as_uint(fv[j]) >> 16);            // trunc bf16
        a0[j] = (lv[j] == ln)      ? (short)0x3F80 : (short)0;    // 1.0 bf16
        a1[j] = (lv[j] == ln + 16) ? (short)0x3F80 : (short)0;
        const float g = ((unsigned)lv[j] < NUM_CLASS) ? fv[j] : 0.0f;
        ss = fmaf(g, fv[j], ss);                                  // gated f^2
    }
    acc0 = __builtin_amdgcn_mfma_f32_16x16x32_bf16(a0, fb, acc0, 0, 0, 0);
    acc1 = __builtin_amdgcn_mfma_f32_16x16x32_bf16(a1, fb, acc1, 0, 0, 0);
}

// ---------------------------------------------------------------------------
// Main kernel. Blocks [0,8): per-batch counts (round-3 proven LDS path).
// Blocks [8, 8+8*32*nks): MFMA class-sum. Block -> (b, dg, ks): 16 d-rows,
// K-slice ks of HW/nks pixels; 4 waves split the K-slice. No hot-loop DS
// (the LDS scatter's ~1 DS instr/element was the 24us residual); 2-deep
// load ring; 4 blocks/CU (16 waves) at nks=4 vs round 8's fatal 1 block/CU.
// ---------------------------------------------------------------------------
__global__ __launch_bounds__(256) void car_main_kernel(
    const float* __restrict__ features, const int* __restrict__ label,
    float* __restrict__ class_sum_part, float* __restrict__ ss_parts,
    float* __restrict__ counts, float* __restrict__ total_parts, int shift)
{
    __shared__ float smem[4 * NUM_CLASS * 64];   // counts: 4 wave-copies; mfma: comb
    __shared__ float red[4];
    const int t = threadIdx.x;
    const int lane = t & 63;
    const int wave = t >> 6;

    if (blockIdx.x < BATCH) {
        // ---- counts path ----
        const int b = blockIdx.x;
        float* __restrict__ smw = smem + wave * (NUM_CLASS * 64);
        for (int i = lane; i < NUM_CLASS * 64; i += 64) smw[i] = 0.0f;
        const int4* __restrict__ lrow = (const int4*)(label + (size_t)b * HW);
        float tv = 0.0f;
        #pragma unroll 2
        for (int i = 0; i < 16; ++i) {
            int4 l = lrow[i * 256 + t];
            if (l.x != 255) tv += 1.0f;
            if ((unsigned)l.x < NUM_CLASS) { float v = smw[l.x * 64 + lane]; smw[l.x * 64 + lane] = v + 1.0f; }
            if (l.y != 255) tv += 1.0f;
            if ((unsigned)l.y < NUM_CLASS) { float v = smw[l.y * 64 + lane]; smw[l.y * 64 + lane] = v + 1.0f; }
            if (l.z != 255) tv += 1.0f;
            if ((unsigned)l.z < NUM_CLASS) { float v = smw[l.z * 64 + lane]; smw[l.z * 64 + lane] = v + 1.0f; }
            if (l.w != 255) tv += 1.0f;
            if ((unsigned)l.w < NUM_CLASS) { float v = smw[l.w * 64 + lane]; smw[l.w * 64 + lane] = v + 1.0f; }
        }
        __syncthreads();
        for (int c = wave; c < NUM_CLASS; c += 4) {
            const int idx = c * 64 + lane;
            float v = smem[idx] + smem[NUM_CLASS * 64 + idx]
                    + smem[2 * NUM_CLASS * 64 + idx] + smem[3 * NUM_CLASS * 64 + idx];
            v = waveReduce(v);
            if (lane == 0) counts[b * NUM_CLASS + c] = v;
        }
        tv = waveReduce(tv);
        if (lane == 0) red[wave] = tv;
        __syncthreads();
        if (t == 0) total_parts[b] = red[0] + red[1] + red[2] + red[3];
        return;
    }

    // ---- MFMA path ----
    const int bid = blockIdx.x - BATCH;
    const int ks  = bid & ((1 << shift) - 1);
    const int dgb = bid >> shift;
    const int dg  = dgb & (NDG - 1);
    const int b   = dgb >> 5;
    const int D0  = dg * 16;
    const int ln  = lane & 15;
    const int l4  = lane >> 4;

    const float* __restrict__ frow = features + ((size_t)(b * DCH + D0 + ln)) * HW;
    const int*   __restrict__ lrow = label + (size_t)b * HW;

    const int NT = HW >> (shift + 7);            // K-tiles per wave (even)
    int pbase = ks * (HW >> shift) + wave * (HW >> (shift + 2)) + l4 * 8;

    f32x4 acc0 = {0.f, 0.f, 0.f, 0.f};
    f32x4 acc1 = {0.f, 0.f, 0.f, 0.f};
    float ss = 0.0f;

    // 2-deep tile ring
    float4 f0a = *(const float4*)(frow + pbase);
    float4 f1a = *(const float4*)(frow + pbase + 4);
    int4   laa = *(const int4*)(lrow + pbase);
    int4   lba = *(const int4*)(lrow + pbase + 4);
    float4 f0b = *(const float4*)(frow + pbase + 32);
    float4 f1b = *(const float4*)(frow + pbase + 36);
    int4   lab = *(const int4*)(lrow + pbase + 32);
    int4   lbb = *(const int4*)(lrow + pbase + 36);

    #pragma unroll 1
    for (int kt = 0; kt < NT - 2; kt += 2) {
        procTile(f0a, f1a, laa, lba, ln, acc0, acc1, ss);
        f0a = *(const float4*)(frow + pbase + 64);
        f1a = *(const float4*)(frow + pbase + 68);
        laa = *(const int4*)(lrow + pbase + 64);
        lba = *(const int4*)(lrow + pbase + 68);
        procTile(f0b, f1b, lab, lbb, ln, acc0, acc1, ss);
        f0b = *(const float4*)(frow + pbase + 96);
        f1b = *(const float4*)(frow + pbase + 100);
        lab = *(const int4*)(lrow + pbase + 96);
        lbb = *(const int4*)(lrow + pbase + 100);
        pbase += 64;
    }
    procTile(f0a, f1a, laa, lba, ln, acc0, acc1, ss);
    procTile(f0b, f1b, lab, lbb, ln, acc0, acc1, ss);

    // Combine the 4 waves' accumulators via LDS.
    #pragma unroll
    for (int r = 0; r < 4; ++r) {
        smem[wave * 512 + lane * 8 + r]     = acc0[r];
        smem[wave * 512 + lane * 8 + 4 + r] = acc1[r];
    }
    ss = waveReduce(ss);
    if (lane == 0) red[wave] = ss;
    __syncthreads();

    if (wave == 0) {
        // C/D layout (m89): col = lane&15 (d), row = (lane>>4)*4 + reg (c)
        float* __restrict__ outp = class_sum_part
            + (size_t)ks * BNCD + (size_t)b * NUM_CLASS * DCH;
        #pragma unroll
        for (int r = 0; r < 4; ++r) {
            const int i0 = lane * 8 + r;
            const float v0 = smem[i0] + smem[512 + i0] + smem[1024 + i0] + smem[1536 + i0];
            const int c0 = l4 * 4 + r;
            outp[(size_t)c0 * DCH + D0 + ln] = v0;
            const int i1 = lane * 8 + 4 + r;
            const float v1 = smem[i1] + smem[512 + i1] + smem[1024 + i1] + smem[1536 + i1];
            const int c1 = 16 + l4 * 4 + r;
            if (c1 < NUM_CLASS) outp[(size_t)c1 * DCH + D0 + ln] = v1;
        }
        if (t == 0) ss_parts[bid] = red[0] + red[1] + red[2] + red[3];
    }
}

// ---------------------------------------------------------------------------
// Finalize (1 block, 1024 threads).
//  0: sum ss_parts[n_mfma].  A: S = sum of nks slices; centers; corr;
//  batch-mean cm.  C: norms.  D: 21x21 cosine sim -> inter.
// ---------------------------------------------------------------------------
__global__ __launch_bounds__(1024) void car_finalize_kernel(
    const float* __restrict__ class_sum_part, const float* __restrict__ counts,
    const float* __restrict__ ss_parts, const float* __restrict__ total_parts,
    float* __restrict__ out, int nks, int n_mfma)
{
    __shared__ float cm[NUM_CLASS * DCH];
    __shared__ float norms[NUM_CLASS];
    __shared__ float redC[16];
    __shared__ float redS[16];
    __shared__ float redB[16];
    const int t = threadIdx.x;
    const int lane = t & 63;
    const int wave = t >> 6;

    float ssp = (t < n_mfma) ? ss_parts[t] : 0.0f;

    float corr = 0.0f;
    for (int p = t; p < NUM_CLASS * DCH; p += 1024) {
        const int c = p >> 9;
        float s = 0.0f;
        #pragma unroll
        for (int b = 0; b < BATCH; ++b) {
            const size_t idx = (size_t)b * NUM_CLASS * DCH + p;
            float S = 0.0f;
            for (int sl = 0; sl < nks; ++sl) S += class_sum_part[(size_t)sl * BNCD + idx];
            float n = counts[b * NUM_CLASS + c];
            float cen = S / (n + EPSF);
            corr += cen * (n * cen - 2.0f * S);
            s += cen;
        }
        cm[p] = s * (1.0f / BATCH);
    }
    corr = waveReduce(corr);
    ssp  = waveReduce(ssp);
    if (lane == 0) { redC[wave] = corr; redS[wave] = ssp; }
    __syncthreads();

    for (int c = wave; c < NUM_CLASS; c += 16) {
        float s = 0.0f;
        #pragma unroll
        for (int k = 0; k < DCH / 64; ++k) {
            float v = cm[c * DCH + k * 64 + lane];
            s += v * v;
        }
        s = waveReduce(s);
        if (lane == 0) norms[c] = fmaxf(sqrtf(s), 1e-12f);
    }
    __syncthreads();

    float interAcc = 0.0f;
    for (int p = wave; p < NUM_CLASS * NUM_CLASS; p += 16) {
        const int c1 = p / NUM_CLASS;
        const int c2 = p % NUM_CLASS;
        if (c1 == c2) continue;
        float s = 0.0f;
        #pragma unroll
        for (int k = 0; k < DCH / 64; ++k)
            s += cm[c1 * DCH + k * 64 + lane] * cm[c2 * DCH + k * 64 + lane];
        s = waveReduce(s);
        if (lane == 0) {
            float sim = s / (norms[c1] * norms[c2]);
            interAcc += fmaxf(sim - 0.5f, 0.0f);
        }
    }
    if (lane == 0) redB[wave] = interAcc;
    __syncthreads();

    if (t == 0) {
        float corrT = 0.0f, interT = 0.0f, ssT = 0.0f, tot = 0.0f;
        #pragma unroll
        for (int w = 0; w < 16; ++w) { corrT += redC[w]; interT += redB[w]; ssT += redS[w]; }
        #pragma unroll
        for (int b = 0; b < BATCH; ++b) tot += total_parts[b];
        out[0] = (ssT + corrT) / (tot + EPSF);
        out[1] = interT / ((float)NUM_CLASS + EPSF);
    }
}

extern "C" void kernel_launch(void* const* d_in, const int* in_sizes, int n_in,
                              void* d_out, int out_size, void* d_ws, size_t ws_size,
                              hipStream_t stream) {
    const float* features = (const float*)d_in[0];
    const int*   label    = (const int*)d_in[1];
    float* out = (float*)d_out;

    // ws layout (floats):
    //   [0 .. 1024)          ss_parts (one per mfma block)
    //   [1024 .. 1032)       total_parts
    //   [1040 .. 1208)       counts (8*21)
    //   [1280 .. 1280+nks*86016)  class_sum_part[nks][8][21][512]
    float* ws             = (float*)d_ws;
    float* ss_parts       = ws + 0;
    float* total_parts    = ws + 1024;
    float* counts         = ws + 1040;
    float* class_sum_part = ws + 1280;

    const size_t need4 = (size_t)(1280 + 4 * (size_t)BNCD) * sizeof(float);
    const int shift = (ws_size >= need4) ? 2 : 1;   // K-split 4 (pref) or 2
    const int nks = 1 << shift;
    const int n_mfma = BATCH * NDG * nks;

    car_main_kernel<<<BATCH + n_mfma, 256, 0, stream>>>(
        features, label, class_sum_part, ss_parts, counts, total_parts, shift);
    car_finalize_kernel<<<1, 1024, 0, stream>>>(
        class_sum_part, counts, ss_parts, total_parts, out, nks, n_mfma);
}

// Round 15
// 77.288 us; speedup vs baseline: 2.1734x; 2.1734x over previous
//
#include <hip/hip_runtime.h>
#include <hip/hip_bf16.h>

#define NUM_CLASS 21
#define IGNORE_L 255
#define EPSF 1e-6f
// Problem dims (fixed by setup_inputs): B=8, D=512, H=W=128 -> HW=16384
#define BATCH 8
#define DCH 512
#define HW 16384
#define NPAIRS (BATCH * DCH / 2)   // 2048 scatter blocks (one per d-pair)

__device__ __forceinline__ float waveReduce(float v) {
    #pragma unroll
    for (int m = 1; m < 64; m <<= 1) v += __shfl_xor(v, m, 64);
    return v;
}

// Per-element float2 LDS RMW (rows d0,d0+1 packed in one b64 slot).
// R and W adjacent per element; within one element step the 64 lanes hit
// distinct addresses (slot = (lane+16k)&63, same k), so the step is
// race-free; steps are ordered by the wave's in-order DS execution.
// Invalid labels clamp to class 0 with gated +0. ss accumulates f^2 for
// both rows (valid elements only).
__device__ __forceinline__ void rmwq(float2* __restrict__ smw,
                                     int s0, int s1, int s2, int s3,
                                     float4 fa, float4 fb, int4 l, float& ss) {
    {
        const bool v = (unsigned)l.x < NUM_CLASS;
        const int a = (v ? l.x : 0) * 64 + s0;
        const float ga = v ? fa.x : 0.0f, gb = v ? fb.x : 0.0f;
        float2 w = smw[a]; w.x += ga; w.y += gb; smw[a] = w;
        ss = fmaf(ga, fa.x, ss); ss = fmaf(gb, fb.x, ss);
    }
    {
        const bool v = (unsigned)l.y < NUM_CLASS;
        const int a = (v ? l.y : 0) * 64 + s1;
        const float ga = v ? fa.y : 0.0f, gb = v ? fb.y : 0.0f;
        float2 w = smw[a]; w.x += ga; w.y += gb; smw[a] = w;
        ss = fmaf(ga, fa.y, ss); ss = fmaf(gb, fb.y, ss);
    }
    {
        const bool v = (unsigned)l.z < NUM_CLASS;
        const int a = (v ? l.z : 0) * 64 + s2;
        const float ga = v ? fa.z : 0.0f, gb = v ? fb.z : 0.0f;
        float2 w = smw[a]; w.x += ga; w.y += gb; smw[a] = w;
        ss = fmaf(ga, fa.z, ss); ss = fmaf(gb, fb.z, ss);
    }
    {
        const bool v = (unsigned)l.w < NUM_CLASS;
        const int a = (v ? l.w : 0) * 64 + s3;
        const float ga = v ? fa.w : 0.0f, gb = v ? fb.w : 0.0f;
        float2 w = smw[a]; w.x += ga; w.y += gb; smw[a] = w;
        ss = fmaf(ga, fa.w, ss); ss = fmaf(gb, fb.w, ss);
    }
}

// ---------------------------------------------------------------------------
// Fused kernel: blocks [0,8) per-batch counts; blocks [8, 8+NPAIRS) handle a
// (b, d0=2*pair) ROW PAIR: labels read once per pair (halves label traffic),
// float2 slots halve DS instruction count vs one-row blocks.
// Per-wave private LDS copies (no atomics; gfx950 ds_add_f32 ~lane-serial).
// 4-deep prefetch ring covers HBM latency at 3 blocks/CU occupancy.
// ---------------------------------------------------------------------------
__global__ __launch_bounds__(256) void car_fused_kernel(
    const float* __restrict__ features, const int* __restrict__ label,
    float* __restrict__ class_sum, float* __restrict__ ss_parts,
    float* __restrict__ counts, float* __restrict__ total_parts)
{
    __shared__ float2 sm[4][NUM_CLASS * 64];
    __shared__ float red[4];
    const int t = threadIdx.x;
    const int lane = t & 63;
    const int wave = t >> 6;
    const int s0 = lane;
    const int s1 = (lane + 16) & 63;
    const int s2 = (lane + 32) & 63;
    const int s3 = (lane + 48) & 63;

    float2* __restrict__ smw = &sm[wave][0];
    #pragma unroll
    for (int i = lane; i < NUM_CLASS * 64; i += 64) smw[i] = make_float2(0.f, 0.f);
    // no sync: each wave touches only its own copy until the merge

    if (blockIdx.x < BATCH) {
        // ---- counts path: fa = ones, fb = 0; slot .x accumulates count ----
        const int b = blockIdx.x;
        const int4* __restrict__ lrow = (const int4*)(label + (size_t)b * HW);
        const float4 f1 = {1.f, 1.f, 1.f, 1.f};
        const float4 f0 = {0.f, 0.f, 0.f, 0.f};
        float tv = 0.0f;
        #pragma unroll 2
        for (int i = 0; i < 16; ++i) {
            int4 l = lrow[i * 256 + t];
            rmwq(smw, s0, s1, s2, s3, f1, f0, l, tv);  // tv += 1 per valid
        }
        __syncthreads();
        for (int c = wave; c < NUM_CLASS; c += 4) {
            const float4 vA = *(const float4*)((const float*)&sm[lane >> 5][c * 64] + (lane & 31) * 4);
            const float4 vB = *(const float4*)((const float*)&sm[2 + (lane >> 5)][c * 64] + (lane & 31) * 4);
            float px = (vA.x + vA.z) + (vB.x + vB.z);
            px = waveReduce(px);
            if (lane == 0) counts[b * NUM_CLASS + c] = px;
        }
        tv = waveReduce(tv);
        if (lane == 0) red[wave] = tv;
        __syncthreads();
        if (t == 0) total_parts[b] = red[0] + red[1] + red[2] + red[3];
        return;
    }

    // ---- scatter path: row pair (b, d0), (b, d0+1) ----
    const int r = blockIdx.x - BATCH;          // 0..NPAIRS-1
    const int b = r >> 8;
    const int d0 = (r & 255) * 2;
    const float4* __restrict__ frow0 = (const float4*)(features + ((size_t)b * DCH + d0) * HW);
    const float4* __restrict__ frow1 = (const float4*)(features + ((size_t)b * DCH + d0 + 1) * HW);
    const int4* __restrict__ lrow = (const int4*)(label + (size_t)b * HW);

    // 4-deep prefetch ring (named regs; runtime-indexed arrays would spill).
    float4 A0 = frow0[0 * 256 + t], B0 = frow1[0 * 256 + t];
    float4 A1 = frow0[1 * 256 + t], B1 = frow1[1 * 256 + t];
    float4 A2 = frow0[2 * 256 + t], B2 = frow1[2 * 256 + t];
    float4 A3 = frow0[3 * 256 + t], B3 = frow1[3 * 256 + t];
    int4 L0 = lrow[0 * 256 + t], L1 = lrow[1 * 256 + t];
    int4 L2 = lrow[2 * 256 + t], L3 = lrow[3 * 256 + t];
    float ss = 0.0f;

    #pragma unroll 1
    for (int i = 0; i < 12; i += 4) {
        rmwq(smw, s0, s1, s2, s3, A0, B0, L0, ss);
        A0 = frow0[(i + 4) * 256 + t]; B0 = frow1[(i + 4) * 256 + t]; L0 = lrow[(i + 4) * 256 + t];
        rmwq(smw, s0, s1, s2, s3, A1, B1, L1, ss);
        A1 = frow0[(i + 5) * 256 + t]; B1 = frow1[(i + 5) * 256 + t]; L1 = lrow[(i + 5) * 256 + t];
        rmwq(smw, s0, s1, s2, s3, A2, B2, L2, ss);
        A2 = frow0[(i + 6) * 256 + t]; B2 = frow1[(i + 6) * 256 + t]; L2 = lrow[(i + 6) * 256 + t];
        rmwq(smw, s0, s1, s2, s3, A3, B3, L3, ss);
        A3 = frow0[(i + 7) * 256 + t]; B3 = frow1[(i + 7) * 256 + t]; L3 = lrow[(i + 7) * 256 + t];
    }
    rmwq(smw, s0, s1, s2, s3, A0, B0, L0, ss);
    rmwq(smw, s0, s1, s2, s3, A1, B1, L1, ss);
    rmwq(smw, s0, s1, s2, s3, A2, B2, L2, ss);
    rmwq(smw, s0, s1, s2, s3, A3, B3, L3, ss);
    __syncthreads();

    // Merge 4 wave-copies x 64 slots per class.
    // Two b128 reads/class cover all 4 copies; .x/.z = row d0, .y/.w = d0+1.
    float* __restrict__ out_base = class_sum + (size_t)b * NUM_CLASS * DCH + d0;
    for (int c = wave; c < NUM_CLASS; c += 4) {
        const float4 vA = *(const float4*)((const float*)&sm[lane >> 5][c * 64] + (lane & 31) * 4);
        const float4 vB = *(const float4*)((const float*)&sm[2 + (lane >> 5)][c * 64] + (lane & 31) * 4);
        float px = (vA.x + vA.z) + (vB.x + vB.z);
        float py = (vA.y + vA.w) + (vB.y + vB.w);
        #pragma unroll
        for (int m = 1; m < 64; m <<= 1) {
            px += __shfl_xor(px, m, 64);
            py += __shfl_xor(py, m, 64);
        }
        if (lane == 0) *(float2*)&out_base[(size_t)c * DCH] = make_float2(px, py);
    }

    ss = waveReduce(ss);
    if (lane == 0) red[wave] = ss;
    __syncthreads();
    if (t == 0) ss_parts[r] = red[0] + red[1] + red[2] + red[3];
}

// ---------------------------------------------------------------------------
// Finalize (1 block, 1024 threads / 16 waves).
//  0: sum ss_parts[2048].
//  A: centers, intra correction corr = sum cen*(n*cen - 2S); batch-mean cm.
//  C: per-class norms of cm.   D: 21x21 cosine sim -> inter loss.
//  out[0] = (ss + corr)/(total+eps); out[1] = sum relu(sim-.5)/(21+eps).
// ---------------------------------------------------------------------------
__global__ __launch_bounds__(1024) void car_finalize_kernel(
    const float* __restrict__ class_sum, const float* __restrict__ counts,
    const float* __restrict__ ss_parts, const float* __restrict__ total_parts,
    float* __restrict__ out)
{
    __shared__ float cm[NUM_CLASS * DCH];
    __shared__ float norms[NUM_CLASS];
    __shared__ float redC[16];
    __shared__ float redS[16];
    __shared__ float redB[16];
    const int t = threadIdx.x;
    const int lane = t & 63;
    const int wave = t >> 6;

    float ssp = 0.0f;
    #pragma unroll
    for (int i = 0; i < NPAIRS / 1024; ++i) ssp += ss_parts[i * 1024 + t];

    float corr = 0.0f;
    for (int p = t; p < NUM_CLASS * DCH; p += 1024) {
        const int c = p >> 9;
        float s = 0.0f;
        #pragma unroll
        for (int b = 0; b < BATCH; ++b) {
            float S = class_sum[(size_t)b * NUM_CLASS * DCH + p];
            float n = counts[b * NUM_CLASS + c];
            float cen = S / (n + EPSF);
            corr += cen * (n * cen - 2.0f * S);
            s += cen;
        }
        cm[p] = s * (1.0f / BATCH);
    }
    corr = waveReduce(corr);
    ssp  = waveReduce(ssp);
    if (lane == 0) { redC[wave] = corr; redS[wave] = ssp; }
    __syncthreads();

    for (int c = wave; c < NUM_CLASS; c += 16) {
        float s = 0.0f;
        #pragma unroll
        for (int k = 0; k < DCH / 64; ++k) {
            float v = cm[c * DCH + k * 64 + lane];
            s += v * v;
        }
        s = waveReduce(s);
        if (lane == 0) norms[c] = fmaxf(sqrtf(s), 1e-12f);
    }
    __syncthreads();

    float interAcc = 0.0f;
    for (int p = wave; p < NUM_CLASS * NUM_CLASS; p += 16) {
        const int c1 = p / NUM_CLASS;
        const int c2 = p % NUM_CLASS;
        if (c1 == c2) continue;
        float s = 0.0f;
        #pragma unroll
        for (int k = 0; k < DCH / 64; ++k)
            s += cm[c1 * DCH + k * 64 + lane] * cm[c2 * DCH + k * 64 + lane];
        s = waveReduce(s);
        if (lane == 0) {
            float sim = s / (norms[c1] * norms[c2]);
            interAcc += fmaxf(sim - 0.5f, 0.0f);
        }
    }
    if (lane == 0) redB[wave] = interAcc;
    __syncthreads();

    if (t == 0) {
        float corrT = 0.0f, interT = 0.0f, ssT = 0.0f, tot = 0.0f;
        #pragma unroll
        for (int w = 0; w < 16; ++w) { corrT += redC[w]; interT += redB[w]; ssT += redS[w]; }
        #pragma unroll
        for (int b = 0; b < BATCH; ++b) tot += total_parts[b];
        out[0] = (ssT + corrT) / (tot + EPSF);
        out[1] = interT / ((float)NUM_CLASS + EPSF);
    }
}

extern "C" void kernel_launch(void* const* d_in, const int* in_sizes, int n_in,
                              void* d_out, int out_size, void* d_ws, size_t ws_size,
                              hipStream_t stream) {
    const float* features = (const float*)d_in[0];
    const int*   label    = (const int*)d_in[1];
    float* out = (float*)d_out;

    // ws layout (floats):
    //   [0 .. 2048)          ss_parts (one per scatter block)
    //   [2048 .. 2056)       total_parts
    //   [2056 .. 2224)       counts (8*21)
    //   [2304 .. 88320)      class_sum[8][21][512]
    float* ws          = (float*)d_ws;
    float* ss_parts    = ws + 0;
    float* total_parts = ws + 2048;
    float* counts      = ws + 2056;
    float* class_sum   = ws + 2304;

    car_fused_kernel<<<NPAIRS + BATCH, 256, 0, stream>>>(
        features, label, class_sum, ss_parts, counts, total_parts);
    car_finalize_kernel<<<1, 1024, 0, stream>>>(class_sum, counts, ss_parts, total_parts, out);
}